// Round 15
// baseline (274.489 us; speedup 1.0000x reference)
//
#include <hip/hip_runtime.h>
#include <hip/hip_fp16.h>
#include <math.h>

// AFM forward, round 15: register-free gather pipelining via global_load_lds.
// Two samples per wave: DMA s0 raw fp32 rows -> LDS (3x width-16 calls,
// chunk c at LDS base + lane*16 per the wave-uniform-base rule), convert s0
// to scaled fp16 rows, ISSUE s1's DMA, run s0's 24-tile loop with s1's
// gather in flight (zero VGPRs held -- fixes r13's spill failure mode),
// convert s1, run s1. Grid 1024 blocks = exactly 4 blocks/CU (LDS 35.5 KB
// caps at 4 too) -> one fully-resident round. Tile loop identical to r12
// (best): pooling folded into MFMA row16 (d[8]), fp16 rows in LDS, 1-ahead
// ds_read prefetch, packed relu-dot2 score, exp2, zero barriers.

#define BB 8192
#define FF 39
#define PP 741
#define NT 24                 // 32-pair tiles per sample; tile 23 has 5 valid
#define RBYTES 48             // scaled fp16 row stride: 32B data + 16B pad
#define RAWSZ 2560            // raw fp32 buffer: 156 chunks x 16B = 2496, pad
#define SCSZ  1872            // FF * RBYTES
#define WLDS  (2*RAWSZ + 2*SCSZ)   // 8864 B per wave

typedef _Float16 f16x8 __attribute__((ext_vector_type(8)));
typedef _Float16 h2    __attribute__((ext_vector_type(2)));
typedef __fp16   hw2   __attribute__((ext_vector_type(2)));
typedef float    f32x4  __attribute__((ext_vector_type(4)));
typedef float    f32x16 __attribute__((ext_vector_type(16)));

struct alignas(16) PijT { unsigned v[32][NT]; };
static constexpr PijT make_pij() {
    PijT t{};
    int p = 0;
    for (int i = 0; i < FF; ++i)
        for (int j = i + 1; j < FF; ++j) {
            t.v[p & 31][p >> 5] =
                ((unsigned)(i * RBYTES) << 16) | (unsigned)(j * RBYTES);
            ++p;
        }
    return t;
}
__device__ constexpr PijT c_pij = make_pij();

static __device__ __forceinline__ h2 cvt2(float lo, float hi) {
    return __builtin_bit_cast(h2, __builtin_amdgcn_cvt_pkrtz(lo, hi));
}
static __device__ __forceinline__ h2 ash2(unsigned d) {
    return __builtin_bit_cast(h2, d);
}
static __device__ __forceinline__ float fdot2f(h2 a, h2 b, float c) {
    return __builtin_amdgcn_fdot2(__builtin_bit_cast(hw2, a),
                                  __builtin_bit_cast(hw2, b), c, false);
}
static __device__ __forceinline__ h2 relu2(h2 x) {
    const h2 zz = {(_Float16)0.f, (_Float16)0.f};
    return __builtin_elementwise_max(x, zz);   // v_pk_max_f16
}

// DMA one sample's 39 raw fp32 rows (156 x 16B chunks) into rawbuf.
// chunk c: row=c>>2, quarter q=c&3; LDS dest = rawbuf + k*1024 + lane*16.
static __device__ __forceinline__ void dma_rows(const float* __restrict__ emb,
                                                int ixlane, int lane,
                                                unsigned char* rawbuf)
{
    #pragma unroll
    for (int k = 0; k < 3; ++k) {
        int c   = k * 64 + lane;
        int row = c >> 2, q = c & 3;
        int ix  = __shfl(ixlane, row < FF ? row : 0);
        const char* g = (const char*)emb + ((size_t)ix * 64 + q * 16);
        if (c < FF * 4) {
            __builtin_amdgcn_global_load_lds(
                (const __attribute__((address_space(1))) void*)g,
                (__attribute__((address_space(3))) void*)(rawbuf + k * 1024),
                16, 0, 0);
        }
    }
}

// convert raw fp32 rows -> scaled fp16 rows (same-wave; compiler inserts
// the vmcnt wait for the outstanding DMA before these ds_reads).
static __device__ __forceinline__ void convert_rows(
    const unsigned char* rawbuf, unsigned char* scbuf, float vlane, int lane)
{
    #pragma unroll
    for (int u0 = 0; u0 < 2; ++u0) {
        int u = u0 * 64 + lane;
        if (u < FF * 2) {
            int row = u >> 1, hh = u & 1;
            float v = __shfl(vlane, row);
            const float4* r4 = (const float4*)(rawbuf + row * 64 + hh * 32);
            float4 e0 = r4[0], e1 = r4[1];
            h2 a0 = cvt2(e0.x * v, e0.y * v);
            h2 a1 = cvt2(e0.z * v, e0.w * v);
            h2 a2 = cvt2(e1.x * v, e1.y * v);
            h2 a3 = cvt2(e1.z * v, e1.w * v);
            uint4 d = make_uint4(__builtin_bit_cast(unsigned, a0),
                                 __builtin_bit_cast(unsigned, a1),
                                 __builtin_bit_cast(unsigned, a2),
                                 __builtin_bit_cast(unsigned, a3));
            *(uint4*)(scbuf + row * RBYTES + hh * 16) = d;
        }
    }
}

// r12's 24-tile fused loop for one sample.
static __device__ __forceinline__ void tile_loop(
    const unsigned char* bpre, const unsigned* po, f16x8 wfrag,
    const f32x16& cinit, h2 hp0, h2 hp1, h2 hp2, h2 hp3, int n,
    float& aw, float& z)
{
    uint4 di = *(const uint4*)(bpre + (po[0] >> 16));
    uint4 dj = *(const uint4*)(bpre + (po[0] & 0xFFFFu));
    #pragma unroll
    for (int t = 0; t < NT; ++t) {
        uint4 diN = di, djN = dj;
        if (t + 1 < NT) {                        // compile-time under unroll
            diN = *(const uint4*)(bpre + (po[t + 1] >> 16));
            djN = *(const uint4*)(bpre + (po[t + 1] & 0xFFFFu));
        }
        h2 m0 = ash2(di.x) * ash2(dj.x);         // v_pk_mul_f16
        h2 m1 = ash2(di.y) * ash2(dj.y);
        h2 m2 = ash2(di.z) * ash2(dj.z);
        h2 m3 = ash2(di.w) * ash2(dj.w);
        union { h2 hh[4]; f16x8 v; } u;
        u.hh[0] = m0; u.hh[1] = m1; u.hh[2] = m2; u.hh[3] = m3;
        f32x16 d = __builtin_amdgcn_mfma_f32_32x32x16_f16(wfrag, u.v,
                                                          cinit, 0, 0, 0);
        h2 c0 = relu2(cvt2(d[0], d[1]));
        h2 c1 = relu2(cvt2(d[2], d[3]));
        h2 c2 = relu2(cvt2(d[4], d[5]));
        h2 c3 = relu2(cvt2(d[6], d[7]));
        float s = fdot2f(c0, hp0,
                  fdot2f(c1, hp1,
                  fdot2f(c2, hp2,
                  fdot2f(c3, hp3, 0.f))));       // v_dot2_f32_f16 x4
        s += __shfl_xor(s, 32);                  // sum the two a-halves
        float w = __builtin_amdgcn_exp2f(s);
        if (t == NT - 1) w = (n < PP - (NT - 1) * 32) ? w : 0.f;
        z  += w;
        aw  = fmaf(w, d[8], aw);   // d[8]: row16 (=bi.p) on h=0, zero on h=1
        di = diN; dj = djN;
    }
}

__global__ __launch_bounds__(256, 4)
void afm_kernel(const int*   __restrict__ fidx,
                const float* __restrict__ fval,
                const float* __restrict__ fow,
                const float* __restrict__ emb,
                const float* __restrict__ bias,
                const float* __restrict__ aw_,   // [E=16][A=16] row-major
                const float* __restrict__ ab_,   // [16]
                const float* __restrict__ ph_,   // [16]
                const float* __restrict__ pp_,   // [16]
                float*       __restrict__ out)
{
    __shared__ __align__(16) unsigned char s_lds[4 * WLDS];   // 35456 B

    const int tid  = threadIdx.x;
    const int wid  = tid >> 6;
    const int lane = tid & 63;
    const int n    = lane & 31;      // pair slot within tile
    const int h    = lane >> 5;      // e-half / k-half
    const int smp0 = blockIdx.x * 8 + wid * 2;

    unsigned char* wbase = s_lds + wid * WLDS;
    unsigned char* raw0  = wbase;
    unsigned char* raw1  = wbase + RAWSZ;
    unsigned char* sc0   = wbase + 2 * RAWSZ;
    unsigned char* sc1   = wbase + 2 * RAWSZ + SCSZ;

    // ---- indices + values + first-order for both samples (upfront) ----
    int ix0 = 0, ix1 = 0; float v0 = 0.f, v1 = 0.f;
    if (lane < FF) {
        ix0 = fidx[smp0 * FF + lane];       v0 = fval[smp0 * FF + lane];
        ix1 = fidx[(smp0 + 1) * FF + lane]; v1 = fval[(smp0 + 1) * FF + lane];
    }
    float fo0 = (lane < FF) ? fow[ix0] * v0 : 0.f;
    float fo1 = (lane < FF) ? fow[ix1] * v1 : 0.f;

    // ---- DMA sample 0, convert it (auto vmcnt wait covers s0 only) ----
    dma_rows(emb, ix0, lane, raw0);
    convert_rows(raw0, sc0, v0, lane);

    // ---- ISSUE sample 1's DMA; it flies under sample 0's tile loop ----
    dma_rows(emb, ix1, lane, raw1);

    // ---- constant fragments (shared by both samples) ----
    const float LOG2E = 1.44269504088896f;
    h2 hp0, hp1, hp2, hp3;
    {
        const f32x4 lo = ((const f32x4*)ph_)[h];
        const f32x4 hi = ((const f32x4*)ph_)[h + 2];
        hp0 = cvt2(lo[0] * LOG2E, lo[1] * LOG2E);
        hp1 = cvt2(lo[2] * LOG2E, lo[3] * LOG2E);
        hp2 = cvt2(hi[0] * LOG2E, hi[1] * LOG2E);
        hp3 = cvt2(hi[2] * LOG2E, hi[3] * LOG2E);
    }
    f32x16 cinit;                   // bias rows a<16; rows >=16 zero
    {
        const f32x4 ab_lo = ((const f32x4*)ab_)[h];
        const f32x4 ab_hi = ((const f32x4*)ab_)[h + 2];
        cinit[0] = ab_lo[0]; cinit[1] = ab_lo[1];
        cinit[2] = ab_lo[2]; cinit[3] = ab_lo[3];
        cinit[4] = ab_hi[0]; cinit[5] = ab_hi[1];
        cinit[6] = ab_hi[2]; cinit[7] = ab_hi[3];
        #pragma unroll
        for (int r = 8; r < 16; ++r) cinit[r] = 0.f;
    }
    f16x8 wfrag;        // A: rows 0..15 = W^T, row 16 = proj_p, 17..31 zero
    {
        float t0 = 0.f, t1 = 0.f, t2 = 0.f, t3 = 0.f,
              t4 = 0.f, t5 = 0.f, t6 = 0.f, t7 = 0.f;
        if (n < 16) {
            const float* base = aw_ + (8 * h) * 16 + n;  // W[k=8h+j][m=n]
            t0 = base[0];   t1 = base[16];  t2 = base[32];  t3 = base[48];
            t4 = base[64];  t5 = base[80];  t6 = base[96];  t7 = base[112];
        } else if (n == 16) {
            const float* base = pp_ + 8 * h;             // p[k=8h+j]
            t0 = base[0]; t1 = base[1]; t2 = base[2]; t3 = base[3];
            t4 = base[4]; t5 = base[5]; t6 = base[6]; t7 = base[7];
        }
        union { h2 hh[4]; f16x8 v; } u;
        u.hh[0] = cvt2(t0, t1); u.hh[1] = cvt2(t2, t3);
        u.hh[2] = cvt2(t4, t5); u.hh[3] = cvt2(t6, t7);
        wfrag = u.v;
    }

    // ---- preload all 24 pair offsets (L1, 6 dwordx4; shared) ----
    unsigned po[NT];
    {
        const uint4* myp4 = (const uint4*)c_pij.v[n];
        #pragma unroll
        for (int g = 0; g < 6; ++g) {
            uint4 q = myp4[g];
            po[4 * g + 0] = q.x; po[4 * g + 1] = q.y;
            po[4 * g + 2] = q.z; po[4 * g + 3] = q.w;
        }
    }

    // ---- sample 0 tile loop (s1's DMA in flight underneath) ----
    float aw0 = 0.f, z0 = 0.f, aw1 = 0.f, z1 = 0.f;
    tile_loop(sc0 + h * 16, po, wfrag, cinit, hp0, hp1, hp2, hp3, n, aw0, z0);

    // ---- convert + run sample 1 (DMA long since landed) ----
    convert_rows(raw1, sc1, v1, lane);
    tile_loop(sc1 + h * 16, po, wfrag, cinit, hp0, hp1, hp2, hp3, n, aw1, z1);

    // ---- final reduce: 6 values in one shuffle block ----
    #pragma unroll
    for (int m = 1; m < 64; m <<= 1) {
        aw0 += __shfl_xor(aw0, m); z0 += __shfl_xor(z0, m);
        fo0 += __shfl_xor(fo0, m);
        aw1 += __shfl_xor(aw1, m); z1 += __shfl_xor(z1, m);
        fo1 += __shfl_xor(fo1, m);
    }
    if (lane == 0) {
        float y0 = bias[0] + fo0 + 2.f * aw0 / z0;
        float y1 = bias[0] + fo1 + 2.f * aw1 / z1;
        out[smp0]     = 1.f / (1.f + __expf(-y0));
        out[smp0 + 1] = 1.f / (1.f + __expf(-y1));
    }
}

extern "C" void kernel_launch(void* const* d_in, const int* in_sizes, int n_in,
                              void* d_out, int out_size, void* d_ws, size_t ws_size,
                              hipStream_t stream) {
    const int*   fidx      = (const int*)  d_in[0];
    const float* fval      = (const float*)d_in[1];
    const float* fow       = (const float*)d_in[2];
    const float* emb_table = (const float*)d_in[3];
    const float* bias      = (const float*)d_in[4];
    const float* attn_w    = (const float*)d_in[5];
    const float* attn_b    = (const float*)d_in[6];
    const float* proj_h    = (const float*)d_in[7];
    const float* proj_p    = (const float*)d_in[8];
    float* out = (float*)d_out;

    afm_kernel<<<BB / 8, 256, 0, stream>>>(fidx, fval, fow, emb_table, bias,
                                           attn_w, attn_b, proj_h, proj_p, out);
}

// Round 16
// 123.828 us; speedup vs baseline: 2.2167x; 2.2167x over previous
//
#include <hip/hip_runtime.h>
#include <hip/hip_fp16.h>
#include <math.h>

// AFM forward, FINAL (= round-12/14 best: JSON 123.9us, kernel ~31.7us).
// One wave = one sample. Pooling folded INTO the MFMA via A-row 16 = proj_p
// (D[16][n] = bi.p arrives in d[8] of h=0 lanes; h=1 lanes read zero-row 20).
// Zero barriers (same-wave LDS ordering); constexpr pair table preloaded to
// registers (6 dwordx4, L1); fp16 scaled rows in LDS (RBYTES=48 pad);
// 1-tile-ahead ds_read prefetch; mfma_f32_32x32x16_f16 (K=16 exact); packed
// relu (v_pk_max_f16) + v_dot2_f32_f16 score; exp2 with h pre-scaled by
// log2(e); single 64-lane shuffle reduce of (aw, z, fo).
//
// Session laws (r6/r13/r15): (1) launch_bounds must leave >=100 VGPR or the
// body spills catastrophically; (2) exactly ONE inlined tile-loop instance
// per kernel -- two-samples-per-wave duplicates the unrolled loop and spills
// regardless of where the prefetch state lives (registers or LDS-DMA).

#define BB 8192
#define FF 39
#define PP 741
#define NT 24                 // 32-pair tiles per sample; tile 23 has 5 valid
#define RBYTES 48             // fp16 row stride: 32B data + 16B pad
#define SBYTES (FF * RBYTES)  // 1872 B per sample

typedef _Float16 f16x8 __attribute__((ext_vector_type(8)));
typedef _Float16 h2    __attribute__((ext_vector_type(2)));
typedef __fp16   hw2   __attribute__((ext_vector_type(2)));  // builtin ABI type
typedef float    f32x4  __attribute__((ext_vector_type(4)));
typedef float    f32x16 __attribute__((ext_vector_type(16)));

// static pair table, transposed: v[n][k] = byte offsets of pair p = k*32+n,
// packed (i*RBYTES)<<16 | (j*RBYTES). Dead slots (p>=741) stay 0 (masked).
struct alignas(16) PijT { unsigned v[32][NT]; };
static constexpr PijT make_pij() {
    PijT t{};
    int p = 0;
    for (int i = 0; i < FF; ++i)
        for (int j = i + 1; j < FF; ++j) {
            t.v[p & 31][p >> 5] =
                ((unsigned)(i * RBYTES) << 16) | (unsigned)(j * RBYTES);
            ++p;
        }
    return t;
}
__device__ constexpr PijT c_pij = make_pij();

static __device__ __forceinline__ h2 cvt2(float lo, float hi) {
    return __builtin_bit_cast(h2, __builtin_amdgcn_cvt_pkrtz(lo, hi));
}
static __device__ __forceinline__ h2 ash2(unsigned d) {
    return __builtin_bit_cast(h2, d);
}
static __device__ __forceinline__ float fdot2f(h2 a, h2 b, float c) {
    return __builtin_amdgcn_fdot2(__builtin_bit_cast(hw2, a),
                                  __builtin_bit_cast(hw2, b), c, false);
}
static __device__ __forceinline__ h2 relu2(h2 x) {
    const h2 zz = {(_Float16)0.f, (_Float16)0.f};
    return __builtin_elementwise_max(x, zz);   // v_pk_max_f16
}

__global__ __launch_bounds__(256, 5)
void afm_kernel(const int*   __restrict__ fidx,
                const float* __restrict__ fval,
                const float* __restrict__ fow,
                const float* __restrict__ emb,
                const float* __restrict__ bias,
                const float* __restrict__ aw_,   // [E=16][A=16] row-major
                const float* __restrict__ ab_,   // [16]
                const float* __restrict__ ph_,   // [16]
                const float* __restrict__ pp_,   // [16]
                float*       __restrict__ out)
{
    __shared__ __align__(16) unsigned char s_emb[4 * SBYTES];  // 7488 B

    const int tid  = threadIdx.x;
    const int wid  = tid >> 6;
    const int lane = tid & 63;
    const int n    = lane & 31;      // pair slot within tile
    const int h    = lane >> 5;      // e-half / k-half
    const int smp  = blockIdx.x * 4 + wid;

    // ---- per-wave: indices + values ----
    int ixr = 0; float vr = 0.f;
    if (lane < FF) {
        ixr = fidx[smp * FF + lane];
        vr  = fval[smp * FF + lane];
    }

    // ---- stage scaled rows as fp16 (78 half-row tasks, same wave) ----
    unsigned char* my = s_emb + wid * SBYTES;
    for (int u = lane; u < FF * 2; u += 64) {
        int row = u >> 1, hh = u & 1;
        int   ix = __shfl(ixr, row);
        float v  = __shfl(vr,  row);
        const float4* src = (const float4*)emb + (size_t)ix * 4 + hh * 2;
        float4 e0 = src[0], e1 = src[1];
        h2 a0 = cvt2(e0.x * v, e0.y * v);
        h2 a1 = cvt2(e0.z * v, e0.w * v);
        h2 a2 = cvt2(e1.x * v, e1.y * v);
        h2 a3 = cvt2(e1.z * v, e1.w * v);
        uint4 d = make_uint4(__builtin_bit_cast(unsigned, a0),
                             __builtin_bit_cast(unsigned, a1),
                             __builtin_bit_cast(unsigned, a2),
                             __builtin_bit_cast(unsigned, a3));
        *(uint4*)(my + row * RBYTES + hh * 16) = d;
    }

    // ---- first-order partial (reduced at the very end with aw,z) ----
    float fo = (lane < FF) ? fow[ixr] * vr : 0.f;

    // ---- constant fragments ----
    const float LOG2E = 1.44269504088896f;
    // packed h coefficients (pre-scaled by log2 e), matching D-reg pair order:
    // regs 0..3 -> a = 4h + r ; regs 4..7 -> a = 8 + 4h + r
    h2 hp0, hp1, hp2, hp3;
    {
        const f32x4 lo = ((const f32x4*)ph_)[h];
        const f32x4 hi = ((const f32x4*)ph_)[h + 2];
        hp0 = cvt2(lo[0] * LOG2E, lo[1] * LOG2E);
        hp1 = cvt2(lo[2] * LOG2E, lo[3] * LOG2E);
        hp2 = cvt2(hi[0] * LOG2E, hi[1] * LOG2E);
        hp3 = cvt2(hi[2] * LOG2E, hi[3] * LOG2E);
    }

    f32x16 cinit;                   // bias in rows a<16; rows >=16 zero
    {                               // (row 16 = proj_p row must have C=0)
        const f32x4 ab_lo = ((const f32x4*)ab_)[h];
        const f32x4 ab_hi = ((const f32x4*)ab_)[h + 2];
        cinit[0] = ab_lo[0]; cinit[1] = ab_lo[1];
        cinit[2] = ab_lo[2]; cinit[3] = ab_lo[3];
        cinit[4] = ab_hi[0]; cinit[5] = ab_hi[1];
        cinit[6] = ab_hi[2]; cinit[7] = ab_hi[3];
        #pragma unroll
        for (int r = 8; r < 16; ++r) cinit[r] = 0.f;
    }

    f16x8 wfrag;        // A: rows 0..15 = W^T, row 16 = proj_p, 17..31 zero
    {
        float t0 = 0.f, t1 = 0.f, t2 = 0.f, t3 = 0.f,
              t4 = 0.f, t5 = 0.f, t6 = 0.f, t7 = 0.f;
        if (n < 16) {
            const float* base = aw_ + (8 * h) * 16 + n;  // W[k=8h+j][m=n]
            t0 = base[0];   t1 = base[16];  t2 = base[32];  t3 = base[48];
            t4 = base[64];  t5 = base[80];  t6 = base[96];  t7 = base[112];
        } else if (n == 16) {
            const float* base = pp_ + 8 * h;             // p[k=8h+j]
            t0 = base[0]; t1 = base[1]; t2 = base[2]; t3 = base[3];
            t4 = base[4]; t5 = base[5]; t6 = base[6]; t7 = base[7];
        }
        union { h2 hh[4]; f16x8 v; } u;
        u.hh[0] = cvt2(t0, t1); u.hh[1] = cvt2(t2, t3);
        u.hh[2] = cvt2(t4, t5); u.hh[3] = cvt2(t6, t7);
        wfrag = u.v;
    }

    // ---- preload all 24 pair offsets into registers (L1, 6 dwordx4) ----
    unsigned po[NT];
    {
        const uint4* myp4 = (const uint4*)c_pij.v[n];
        #pragma unroll
        for (int g = 0; g < 6; ++g) {
            uint4 q = myp4[g];
            po[4 * g + 0] = q.x; po[4 * g + 1] = q.y;
            po[4 * g + 2] = q.z; po[4 * g + 3] = q.w;
        }
    }

    // ---- main loop: 24 tiles, software-pipelined LDS reads (1 tile ahead) --
    const unsigned char* bpre = my + h * 16;    // this lane's e-half
    float aw = 0.f;                             // sum_p w_p * (bi_p . p)
    float z  = 0.f;                             // sum_p w_p (x2 across halves)

    uint4 di = *(const uint4*)(bpre + (po[0] >> 16));
    uint4 dj = *(const uint4*)(bpre + (po[0] & 0xFFFFu));

    #pragma unroll
    for (int t = 0; t < NT; ++t) {
        uint4 diN = di, djN = dj;
        if (t + 1 < NT) {                        // compile-time under unroll
            diN = *(const uint4*)(bpre + (po[t + 1] >> 16));
            djN = *(const uint4*)(bpre + (po[t + 1] & 0xFFFFu));
        }
        h2 m0 = ash2(di.x) * ash2(dj.x);         // v_pk_mul_f16
        h2 m1 = ash2(di.y) * ash2(dj.y);
        h2 m2 = ash2(di.z) * ash2(dj.z);
        h2 m3 = ash2(di.w) * ash2(dj.w);
        union { h2 hh[4]; f16x8 v; } u;
        u.hh[0] = m0; u.hh[1] = m1; u.hh[2] = m2; u.hh[3] = m3;
        f32x16 d = __builtin_amdgcn_mfma_f32_32x32x16_f16(wfrag, u.v,
                                                          cinit, 0, 0, 0);
        h2 c0 = relu2(cvt2(d[0], d[1]));
        h2 c1 = relu2(cvt2(d[2], d[3]));
        h2 c2 = relu2(cvt2(d[4], d[5]));
        h2 c3 = relu2(cvt2(d[6], d[7]));
        float s = fdot2f(c0, hp0,
                  fdot2f(c1, hp1,
                  fdot2f(c2, hp2,
                  fdot2f(c3, hp3, 0.f))));       // v_dot2_f32_f16 x4
        s += __shfl_xor(s, 32);                  // sum the two a-halves
        float w = __builtin_amdgcn_exp2f(s);
        if (t == NT - 1) w = (n < PP - (NT - 1) * 32) ? w : 0.f;
        z  += w;
        aw  = fmaf(w, d[8], aw);   // d[8]: row16 (=bi.p) on h=0, zero on h=1
        di = diN; dj = djN;
    }

    // ---- final reduce: aw, z, fo in one shuffle block ----
    #pragma unroll
    for (int m = 1; m < 64; m <<= 1) {
        aw += __shfl_xor(aw, m);
        z  += __shfl_xor(z, m);
        fo += __shfl_xor(fo, m);
    }
    if (lane == 0) {
        // lane-sum aw counts each pair once; lane-sum z = 2*Z.
        float y = bias[0] + fo + 2.f * aw / z;
        out[smp] = 1.f / (1.f + __expf(-y));
    }
}

extern "C" void kernel_launch(void* const* d_in, const int* in_sizes, int n_in,
                              void* d_out, int out_size, void* d_ws, size_t ws_size,
                              hipStream_t stream) {
    const int*   fidx      = (const int*)  d_in[0];
    const float* fval      = (const float*)d_in[1];
    const float* fow       = (const float*)d_in[2];
    const float* emb_table = (const float*)d_in[3];
    const float* bias      = (const float*)d_in[4];
    const float* attn_w    = (const float*)d_in[5];
    const float* attn_b    = (const float*)d_in[6];
    const float* proj_h    = (const float*)d_in[7];
    const float* proj_p    = (const float*)d_in[8];
    float* out = (float*)d_out;

    afm_kernel<<<BB / 4, 256, 0, stream>>>(fidx, fval, fow, emb_table, bias,
                                           attn_w, attn_b, proj_h, proj_p, out);
}